// Round 12
// baseline (140.229 us; speedup 1.0000x reference)
//
#include <hip/hip_runtime.h>
#include <stdint.h>

#define BATCH 32
#define NANCH 8400
#define NCLS 80
#define KPRE 1000
#define KPAD 1024
#define MAXDET 100
#define CONF 0.2f
#define IOUTHR 0.7f

typedef unsigned long long ull;

// monotonic map: float -> uint32 preserving total order
__device__ __forceinline__ uint32_t fmap(float f) {
  uint32_t u = __float_as_uint(f);
  return (u & 0x80000000u) ? ~u : (u | 0x80000000u);
}

__device__ __forceinline__ ull readlane64(ull v, int lane) {
  uint32_t lo = __builtin_amdgcn_readlane((uint32_t)(v & 0xffffffffull), lane);
  uint32_t hi = __builtin_amdgcn_readlane((uint32_t)(v >> 32), lane);
  return ((ull)hi << 32) | (ull)lo;
}

__device__ __forceinline__ float readlane_f(float v, int lane) {
  return __uint_as_float(__builtin_amdgcn_readlane(__float_as_uint(v), lane));
}

// ---------------- Kernel 1: class score max/argmax, 4 lanes per row ----------------
__global__ __launch_bounds__(256) void k_score(
    const float* __restrict__ pcls,     // [B][N][80]
    float* __restrict__ g_scores,       // [B][N]
    int* __restrict__ g_cls)            // [B][N]
{
  int g4 = blockIdx.x * blockDim.x + threadIdx.x;
  if (g4 >= BATCH * NANCH * 4) return;
  int row = g4 >> 2;
  int part = g4 & 3;   // 20 classes per part

  const float4* pc = (const float4*)(pcls + (size_t)row * NCLS) + part * 5;
  float best = -3.402823466e38f;
  int bidx = 0;
  #pragma unroll
  for (int k = 0; k < 5; ++k) {
    float4 v = pc[k];
    int base = part * 20 + 4 * k;
    if (v.x > best) { best = v.x; bidx = base + 0; }
    if (v.y > best) { best = v.y; bidx = base + 1; }
    if (v.z > best) { best = v.z; bidx = base + 2; }
    if (v.w > best) { best = v.w; bidx = base + 3; }
  }
  // reduce across the 4-lane group; exact first-occurrence tie rule
  #pragma unroll
  for (int d = 1; d <= 2; d <<= 1) {
    float ob = __shfl_xor(best, d);
    int oi = __shfl_xor(bidx, d);
    if (ob > best || (ob == best && oi < bidx)) { best = ob; bidx = oi; }
  }
  if (part == 0) {
    g_scores[row] = best;
    g_cls[row] = bidx;
  }
}

// ---------------- Kernel 2: exact stable top-1000 per batch ----------------
// composite 46-bit key: (fmap(score) << 14) | (NANCH-1-i). All keys distinct.
// All real keys have bit45 set (scores >= 0 -> fmap bit31 set), so bisection
// starts at lo = 2^45 with invariant cnt(lo) = 8400 >= KPRE.
#define NITER3 15   // 3 bits per round: 8^15 = 2^45
#define NQ 9        // ceil(8400/1024)

__global__ __launch_bounds__(1024) void k_topk(
    const float* __restrict__ g_scores,
    const int* __restrict__ g_cls,
    const float* __restrict__ g_dist_in,   // [B][N][1]
    float* __restrict__ g_tscore,          // [B][KPAD]
    int* __restrict__ g_tn,                // [B][KPAD] selected anchor index
    int* __restrict__ g_tcls,              // [B][KPAD]
    float* __restrict__ g_tdist)           // [B][KPAD]
{
  int b = blockIdx.x;
  int tid = threadIdx.x;
  int lane = tid & 63;
  __shared__ float ls[NANCH];
  __shared__ ull skeys[KPAD];
  __shared__ ull s_cntA[NITER3];   // C1..C4, 16-bit fields
  __shared__ ull s_cntB[NITER3];   // C5..C7, 16-bit fields
  __shared__ int s_pos;

  const float* sc = g_scores + (size_t)b * NANCH;

  ull key[NQ];
  #pragma unroll
  for (int q = 0; q < NQ; ++q) {
    int i = tid + q * 1024;
    if (i < NANCH) {
      float x = sc[i];
      ls[i] = x;
      key[q] = ((ull)fmap(x) << 14) | (ull)(uint32_t)(NANCH - 1 - i);
    } else {
      key[q] = 0ull;   // below 2^45, never selected
    }
  }
  if (tid < NITER3) { s_cntA[tid] = 0ull; s_cntB[tid] = 0ull; }
  if (tid == 0) s_pos = 0;
  __syncthreads();

  // 8-way bisection for exact 1000th-largest key: 15 rounds, 1 barrier each.
  // invariant: cnt(lo) >= KPRE, cnt(lo+width) < KPRE; terminal width = 1.
  ull lo = 1ull << 45, width = 1ull << 45;
  for (int it = 0; it < NITER3; ++it) {
    ull d = width >> 3;
    int c1 = 0, c2 = 0, c3 = 0, c4 = 0, c5 = 0, c6 = 0, c7 = 0;
    ull t1 = lo + d, t2 = lo + 2 * d, t3 = lo + 3 * d, t4 = lo + 4 * d;
    ull t5 = lo + 5 * d, t6 = lo + 6 * d, t7 = lo + 7 * d;
    #pragma unroll
    for (int q = 0; q < NQ; ++q) {
      ull k = key[q];
      c1 += (k >= t1) ? 1 : 0;
      c2 += (k >= t2) ? 1 : 0;
      c3 += (k >= t3) ? 1 : 0;
      c4 += (k >= t4) ? 1 : 0;
      c5 += (k >= t5) ? 1 : 0;
      c6 += (k >= t6) ? 1 : 0;
      c7 += (k >= t7) ? 1 : 0;
    }
    ull pA = (ull)c1 | ((ull)c2 << 16) | ((ull)c3 << 32) | ((ull)c4 << 48);
    ull pB = (ull)c5 | ((ull)c6 << 16) | ((ull)c7 << 32);
    #pragma unroll
    for (int off = 32; off > 0; off >>= 1) {
      pA += __shfl_down(pA, off);
      pB += __shfl_down(pB, off);
    }
    if (lane == 0) {
      atomicAdd(&s_cntA[it], pA);
      atomicAdd(&s_cntB[it], pB);
    }
    __syncthreads();
    ull CA = s_cntA[it], CB = s_cntB[it];
    int C1 = (int)(CA & 0xFFFFull), C2 = (int)((CA >> 16) & 0xFFFFull);
    int C3 = (int)((CA >> 32) & 0xFFFFull), C4 = (int)(CA >> 48);
    int C5 = (int)(CB & 0xFFFFull), C6 = (int)((CB >> 16) & 0xFFFFull);
    int C7 = (int)((CB >> 32) & 0xFFFFull);
    int step;
    if      (C7 >= KPRE) step = 7;
    else if (C6 >= KPRE) step = 6;
    else if (C5 >= KPRE) step = 5;
    else if (C4 >= KPRE) step = 4;
    else if (C3 >= KPRE) step = 3;
    else if (C2 >= KPRE) step = 2;
    else if (C1 >= KPRE) step = 1;
    else                 step = 0;
    lo += (ull)step * d;
    width = d;
  }
  // lo == exact 1000th largest key; exactly KPRE keys >= lo

  // compact selected keys to LDS
  #pragma unroll
  for (int q = 0; q < NQ; ++q) {
    bool sel = (key[q] >= lo);
    ull m = __ballot(sel);
    int base = 0;
    if (lane == 0) base = atomicAdd(&s_pos, __popcll(m));
    base = __shfl(base, 0);
    if (sel) skeys[base + __popcll(m & ((1ull << lane) - 1ull))] = key[q];
  }
  if (tid >= KPRE) skeys[tid] = 0ull;
  __syncthreads();

  // bitonic sort 1024 keys descending — regs + shfl for j<=32, LDS for j>=64
  ull K = skeys[tid];
  for (int k = 2; k <= KPAD; k <<= 1) {
    bool descDir = ((tid & k) == 0);
    for (int j = k >> 1; j > 0; j >>= 1) {
      ull P;
      if (j >= 64) {
        __syncthreads();
        skeys[tid] = K;
        __syncthreads();
        P = skeys[tid ^ j];
      } else {
        P = __shfl_xor(K, j);
      }
      bool iAmLow = (tid & j) == 0;
      bool takeMax = (iAmLow == descDir);
      bool pGreater = P > K;
      if (takeMax == pGreater) K = P;
    }
  }

  if (tid < KPRE) {
    int n = (NANCH - 1) - (int)(uint32_t)(K & 0x3FFFull);
    size_t src = (size_t)b * NANCH + n;
    size_t dst = (size_t)b * KPAD + tid;
    g_tscore[dst] = ls[n];
    g_tn[dst] = n;
    g_tcls[dst] = g_cls[src];
    g_tdist[dst] = g_dist_in[src];
  }
}

// ---------------- Kernel 2b: DFL box decode for selected anchors only ----------------
__global__ __launch_bounds__(256) void k_boxdec(
    const float* __restrict__ pboxes,   // [B][N][64]
    const int* __restrict__ g_tn,       // [B][KPAD]
    float4* __restrict__ g_tbox)        // [B][KPAD]
{
  int gid = blockIdx.x * blockDim.x + threadIdx.x;
  if (gid >= BATCH * KPRE) return;
  int b = gid / KPRE;
  int s = gid % KPRE;
  int n = g_tn[(size_t)b * KPAD + s];

  const float4* pb = (const float4*)(pboxes + ((size_t)b * NANCH + n) * 64);
  float dist[4];
  #pragma unroll
  for (int k = 0; k < 4; ++k) {
    float v[16];
    #pragma unroll
    for (int q = 0; q < 4; ++q) {
      float4 t = pb[k * 4 + q];
      v[q * 4 + 0] = t.x; v[q * 4 + 1] = t.y; v[q * 4 + 2] = t.z; v[q * 4 + 3] = t.w;
    }
    float m = v[0];
    #pragma unroll
    for (int r = 1; r < 16; ++r) m = fmaxf(m, v[r]);
    float e[16];
    float su = 0.f;
    #pragma unroll
    for (int r = 0; r < 16; ++r) { e[r] = expf(v[r] - m); su += e[r]; }
    float acc = 0.f;
    #pragma unroll
    for (int r = 0; r < 16; ++r) acc += (e[r] / su) * (float)r;
    dist[k] = acc;
  }

  int n0, W; float sf;
  if (n < 6400)      { n0 = n;        W = 80; sf = 8.f;  }
  else if (n < 8000) { n0 = n - 6400; W = 40; sf = 16.f; }
  else               { n0 = n - 8000; W = 20; sf = 32.f; }
  float ax = (float)(n0 % W) + 0.5f;
  float ay = (float)(n0 / W) + 0.5f;

  float4 bx;
  bx.x = (ax - dist[0]) * sf;
  bx.y = (ay - dist[1]) * sf;
  bx.z = (ax + dist[2]) * sf;
  bx.w = (ay + dist[3]) * sf;

  g_tbox[(size_t)b * KPAD + s] = bx;
}

// ---------------- Kernel 3: suppression bit-matrix, one wave per (c,w,half) ----------------
// 136 upper-triangle (c,w) pairs x 2 half-chunks = 272 wave-tasks per batch.
// Lower-triangle g_sup words are NEVER written (always 0 semantically); k_nms masks them.
#define NPAIRS 136

__global__ __launch_bounds__(256) void k_iou(
    const float4* __restrict__ g_tbox,
    ull* __restrict__ g_sup,              // [B][KPAD][16] row-major (w>=c words only)
    ull* __restrict__ g_diag)             // [B][16][64] diag blocks
{
  int b = blockIdx.x;
  int wave = threadIdx.x >> 6;
  int lane = threadIdx.x & 63;
  int t = blockIdx.y * 4 + wave;          // 68*4 = 272 tasks exactly
  int p = t >> 1;                         // pair 0..135
  int h = t & 1;                          // half-chunk 0/1
  // p -> (c, w): enumerate c=0..15, w=c..15
  int c = 0, base = 0;
  while (p >= base + (16 - c)) { base += 16 - c; ++c; }
  int w = c + (p - base);

  const float4* tb = g_tbox + (size_t)b * KPAD;

  // column box (lane j)
  int j = w * 64 + lane;
  bool jv = j < KPRE;
  float4 bj = jv ? tb[j] : make_float4(0.f, 0.f, 0.f, 0.f);
  float aj = (bj.z - bj.x) * (bj.w - bj.y);

  // row box (lane i) — broadcast source registers
  int i = c * 64 + lane;
  float4 bi = (i < KPRE) ? tb[i] : make_float4(0.f, 0.f, 0.f, 0.f);
  float ai = (bi.z - bi.x) * (bi.w - bi.y);

  int rows = min(64, KPRE - c * 64);      // uniform (64, or 40 for c=15)
  int lo_ii = h * 32;
  int hi_ii = min(lo_ii + 32, rows);
  ull myword = 0;
  #pragma unroll 4
  for (int ii = lo_ii; ii < hi_ii; ++ii) {
    int irow = c * 64 + ii;               // uniform
    float rx = readlane_f(bi.x, ii);
    float ry = readlane_f(bi.y, ii);
    float rz = readlane_f(bi.z, ii);
    float rw = readlane_f(bi.w, ii);
    float ra = readlane_f(ai, ii);
    bool pred = false;
    if (jv && j > irow) {
      float ltx = fmaxf(rx, bj.x);
      float lty = fmaxf(ry, bj.y);
      float rbx = fminf(rz, bj.z);
      float rby = fminf(rw, bj.w);
      float wx = fmaxf(rbx - ltx, 0.f);
      float wy = fmaxf(rby - lty, 0.f);
      float inter = wx * wy;
      float den = ((ra + aj) - inter) + 1e-7f;
      pred = (inter / den) > IOUTHR;
    }
    ull word = __ballot(pred);
    if (lane == ii) myword = word;
  }

  int myrow = c * 64 + lane;
  if ((lane >> 5) == h && myrow < KPRE) {
    g_sup[((size_t)b * KPAD + myrow) * 16 + w] = myword;
    if (w == c) g_diag[((size_t)b * 16 + c) * 64 + lane] = myword;
  }
}

// ---------------- Kernel 4: scalar-chain NMS + parallel selection + output ----------------
__global__ __launch_bounds__(64) void k_nms(
    const ull* __restrict__ g_sup,
    const ull* __restrict__ g_diag,
    const float* __restrict__ g_tscore,
    const float4* __restrict__ g_tbox,
    const int* __restrict__ g_tcls,
    const float* __restrict__ g_tdist,
    float* __restrict__ out)
{
  int b = blockIdx.x;
  int lane = threadIdx.x;
  __shared__ __align__(16) ull rowbuf[2][64 * 16];   // 16 KB double buffer
  __shared__ float s_score[KPAD];
  __shared__ ull s_keptw[16];
  __shared__ ull s_valid[16];
  __shared__ int s_vpre[17];
  __shared__ int s_ipre[17];
  __shared__ int s_sel[MAXDET];
  __shared__ int s_flag[MAXDET];

  for (int t = lane; t < KPAD; t += 64)
    s_score[t] = g_tscore[(size_t)b * KPAD + t];

  const char* supb = (const char*)(g_sup + (size_t)b * KPAD * 16);
  const ull* diagb = g_diag + (size_t)b * 16 * 64;

  // prefetch chunk 0 (8 KB) into rowbuf[0] via global_load_lds width-16
  #pragma unroll
  for (int k = 0; k < 8; ++k) {
    const void* gp = supb + (size_t)k * 1024 + (size_t)lane * 16;
    void* lp = (char*)&rowbuf[0][0] + k * 1024;
    __builtin_amdgcn_global_load_lds(
        (const __attribute__((address_space(1))) uint32_t*)gp,
        (__attribute__((address_space(3))) uint32_t*)lp, 16, 0, 0);
  }
  ull diag = diagb[0 * 64 + lane];   // diag words for chunk 0

  // rem4: lane (q=lane>>4, w=lane&15) accumulates word w over kept rows ii with (ii&3)==q
  ull rem4 = 0;
  int w = lane & 15;
  int q = lane >> 4;
  int cur = 0;

  for (int c = 0; c < 16; ++c) {
    asm volatile("s_waitcnt vmcnt(0)" ::: "memory");  // chunk c staged, diag ready

    ull diag_next = 0;
    if (c < 15) {
      #pragma unroll
      for (int k = 0; k < 8; ++k) {
        const void* gp = supb + (size_t)(c + 1) * 8192 + (size_t)k * 1024 + (size_t)lane * 16;
        void* lp = (char*)&rowbuf[cur ^ 1][0] + k * 1024;
        __builtin_amdgcn_global_load_lds(
            (const __attribute__((address_space(1))) uint32_t*)gp,
            (__attribute__((address_space(3))) uint32_t*)lp, 16, 0, 0);
      }
      diag_next = diagb[(c + 1) * 64 + lane];
    }

    // removed word for this chunk from cross-chunk accumulation
    ull remw = readlane64(rem4, c) | readlane64(rem4, c + 16) |
               readlane64(rem4, c + 32) | readlane64(rem4, c + 48);
    ull chunkmask = (c == 15) ? ((1ull << (KPRE - 15 * 64)) - 1ull) : ~0ull;
    ull alive = ~remw & chunkmask;

    // serial greedy chain — wave-uniform scalar ops + readlane, nothing else
    ull kept = 0;
    while (alive) {
      int ii = __builtin_ctzll(alive);
      kept |= 1ull << ii;
      ull wcur = readlane64(diag, ii);
      alive &= ~(wcur | (1ull << ii));
    }
    if (lane == 0) s_keptw[c] = kept;

    // deferred parallel accumulation: OR upper-triangle words (w >= c) of kept rows.
    // Words w < c of rows in chunk c are semantically 0 and are NOT written by k_iou.
    #pragma unroll
    for (int t = 0; t < 16; ++t) {
      int ii = q + t * 4;
      ull v = rowbuf[cur][ii * 16 + w];    // always load (pipelined); predicated use
      if (w >= c && ((kept >> ii) & 1ull)) rem4 |= v;
    }

    cur ^= 1;
    diag = diag_next;
  }
  __syncthreads();

  // valid mask: kept && score > CONF
  for (int k = 0; k < 16; ++k) {
    int c = k * 64 + lane;
    bool sv = (c < KPRE) && (s_score[c] > CONF);
    ull m = __ballot(sv) & s_keptw[k];
    if (lane == 0) s_valid[k] = m;
  }
  __syncthreads();

  // prefix counts (valid / invalid among c < KPRE)
  if (lane == 0) {
    int v = 0, iv = 0;
    for (int k = 0; k < 16; ++k) {
      s_vpre[k] = v; s_ipre[k] = iv;
      int nval = (k == 15) ? (KPRE - 15 * 64) : 64;
      int pv = __popcll(s_valid[k]);
      v += pv; iv += nval - pv;
    }
    s_vpre[16] = v; s_ipre[16] = iv;
  }
  __syncthreads();

  // parallel scatter: valid entries in array order, then invalid (tied -1.0)
  int totValid = s_vpre[16];
  for (int k = 0; k < 16; ++k) {
    int c = k * 64 + lane;
    if (c >= KPRE) continue;
    ull wv = s_valid[k];
    ull ltmask = (1ull << lane) - 1ull;
    bool v = (wv >> lane) & 1ull;
    int below = __popcll(wv & ltmask);
    if (v) {
      int rank = s_vpre[k] + below;
      if (rank < MAXDET) { s_sel[rank] = c; s_flag[rank] = 1; }
    } else {
      int rank = totValid + s_ipre[k] + (lane - below);
      if (rank < MAXDET) { s_sel[rank] = c; s_flag[rank] = 0; }
    }
  }
  __syncthreads();

  float* obox = out;                                 // [B][100][4]
  float* osc  = out + (size_t)BATCH * MAXDET * 4;    // [B][100]
  float* ocls = out + (size_t)BATCH * MAXDET * 5;    // [B][100]
  float* odst = out + (size_t)BATCH * MAXDET * 6;    // [B][100][1]
  float* oval = out + (size_t)BATCH * MAXDET * 7;    // [B][100]

  for (int s = lane; s < MAXDET; s += 64) {
    int i = s_sel[s];
    int fl = s_flag[s];
    size_t src = (size_t)b * KPAD + i;
    float4 bx = g_tbox[src];
    float scv = fl ? s_score[i] : -1.0f;
    float clv = (float)g_tcls[src];
    float ddv = g_tdist[src];
    size_t o = (size_t)b * MAXDET + s;
    obox[o * 4 + 0] = bx.x;
    obox[o * 4 + 1] = bx.y;
    obox[o * 4 + 2] = bx.z;
    obox[o * 4 + 3] = bx.w;
    osc[o] = scv;
    ocls[o] = clv;
    odst[o] = ddv;
    oval[o] = fl ? 1.0f : 0.0f;
  }
}

extern "C" void kernel_launch(void* const* d_in, const int* in_sizes, int n_in,
                              void* d_out, int out_size, void* d_ws, size_t ws_size,
                              hipStream_t stream) {
  const float* pboxes = (const float*)d_in[0];   // (32,8400,64)
  const float* pcls   = (const float*)d_in[1];   // (32,8400,80)
  const float* pdist  = (const float*)d_in[2];   // (32,8400,1)
  // d_in[3] = images, unused by the reference computation
  float* out = (float*)d_out;

  char* ws = (char*)d_ws;
  size_t nBN = (size_t)BATCH * NANCH;
  size_t off = 0;
  float*  g_scores = (float*)(ws + off);  off += nBN * 4;
  int*    g_cls    = (int*)(ws + off);    off += nBN * 4;
  float*  g_tscore = (float*)(ws + off);  off += (size_t)BATCH * KPAD * 4;
  float4* g_tbox   = (float4*)(ws + off); off += (size_t)BATCH * KPAD * 16;
  int*    g_tn     = (int*)(ws + off);    off += (size_t)BATCH * KPAD * 4;
  int*    g_tcls   = (int*)(ws + off);    off += (size_t)BATCH * KPAD * 4;
  float*  g_tdist  = (float*)(ws + off);  off += (size_t)BATCH * KPAD * 4;
  ull*    g_sup    = (ull*)(ws + off);    off += (size_t)BATCH * KPAD * 16 * 8;
  ull*    g_diag   = (ull*)(ws + off);    off += (size_t)BATCH * 16 * 64 * 8;

  int total4 = BATCH * NANCH * 4;
  k_score<<<(total4 + 255) / 256, 256, 0, stream>>>(pcls, g_scores, g_cls);
  k_topk<<<BATCH, 1024, 0, stream>>>(g_scores, g_cls, pdist,
                                     g_tscore, g_tn, g_tcls, g_tdist);
  k_boxdec<<<(BATCH * KPRE + 255) / 256, 256, 0, stream>>>(pboxes, g_tn, g_tbox);
  dim3 giou(BATCH, (NPAIRS * 2) / 4);   // 68 blocks/batch
  k_iou<<<giou, 256, 0, stream>>>(g_tbox, g_sup, g_diag);
  k_nms<<<BATCH, 64, 0, stream>>>(g_sup, g_diag, g_tscore, g_tbox, g_tcls, g_tdist, out);
}

// Round 13
// 133.504 us; speedup vs baseline: 1.0504x; 1.0504x over previous
//
#include <hip/hip_runtime.h>
#include <stdint.h>

#define BATCH 32
#define NANCH 8400
#define NCLS 80
#define KPRE 1000
#define KPAD 1024
#define MAXDET 100
#define CONF 0.2f
#define IOUTHR 0.7f

typedef unsigned long long ull;

// monotonic map: float -> uint32 preserving total order
__device__ __forceinline__ uint32_t fmap(float f) {
  uint32_t u = __float_as_uint(f);
  return (u & 0x80000000u) ? ~u : (u | 0x80000000u);
}

__device__ __forceinline__ ull readlane64(ull v, int lane) {
  uint32_t lo = __builtin_amdgcn_readlane((uint32_t)(v & 0xffffffffull), lane);
  uint32_t hi = __builtin_amdgcn_readlane((uint32_t)(v >> 32), lane);
  return ((ull)hi << 32) | (ull)lo;
}

__device__ __forceinline__ float readlane_f(float v, int lane) {
  return __uint_as_float(__builtin_amdgcn_readlane(__float_as_uint(v), lane));
}

// ---------------- Kernel 1: class score max/argmax, 4 lanes per row ----------------
__global__ __launch_bounds__(256) void k_score(
    const float* __restrict__ pcls,     // [B][N][80]
    float* __restrict__ g_scores,       // [B][N]
    int* __restrict__ g_cls)            // [B][N]
{
  int g4 = blockIdx.x * blockDim.x + threadIdx.x;
  if (g4 >= BATCH * NANCH * 4) return;
  int row = g4 >> 2;
  int part = g4 & 3;   // 20 classes per part

  const float4* pc = (const float4*)(pcls + (size_t)row * NCLS) + part * 5;
  float best = -3.402823466e38f;
  int bidx = 0;
  #pragma unroll
  for (int k = 0; k < 5; ++k) {
    float4 v = pc[k];
    int base = part * 20 + 4 * k;
    if (v.x > best) { best = v.x; bidx = base + 0; }
    if (v.y > best) { best = v.y; bidx = base + 1; }
    if (v.z > best) { best = v.z; bidx = base + 2; }
    if (v.w > best) { best = v.w; bidx = base + 3; }
  }
  // reduce across the 4-lane group; exact first-occurrence tie rule
  #pragma unroll
  for (int d = 1; d <= 2; d <<= 1) {
    float ob = __shfl_xor(best, d);
    int oi = __shfl_xor(bidx, d);
    if (ob > best || (ob == best && oi < bidx)) { best = ob; bidx = oi; }
  }
  if (part == 0) {
    g_scores[row] = best;
    g_cls[row] = bidx;
  }
}

// ---------------- Kernel 2: exact stable top-1000 per batch (bitonic, R7/R11 config) ----------------
// composite 46-bit key: (fmap(score) << 14) | (NANCH-1-i). All keys distinct.
#define NITER2 23   // 2 bits per round: 4^23 = 2^46
#define NQ 9        // ceil(8400/1024)

__global__ __launch_bounds__(1024) void k_topk(
    const float* __restrict__ g_scores,
    const int* __restrict__ g_cls,
    const float* __restrict__ g_dist_in,   // [B][N][1]
    float* __restrict__ g_tscore,          // [B][KPAD]
    int* __restrict__ g_tn,                // [B][KPAD] selected anchor index
    int* __restrict__ g_tcls,              // [B][KPAD]
    float* __restrict__ g_tdist)           // [B][KPAD]
{
  int b = blockIdx.x;
  int tid = threadIdx.x;
  int lane = tid & 63;
  __shared__ float ls[NANCH];
  __shared__ ull skeys[KPAD];
  __shared__ ull s_cnt[NITER2];
  __shared__ int s_pos;

  const float* sc = g_scores + (size_t)b * NANCH;

  ull key[NQ];
  #pragma unroll
  for (int q = 0; q < NQ; ++q) {
    int i = tid + q * 1024;
    if (i < NANCH) {
      float x = sc[i];
      ls[i] = x;
      key[q] = ((ull)fmap(x) << 14) | (ull)(uint32_t)(NANCH - 1 - i);
    } else {
      key[q] = 0ull;
    }
  }
  if (tid < NITER2) s_cnt[tid] = 0ull;
  if (tid == 0) s_pos = 0;
  __syncthreads();

  // 4-way bisection, 23 rounds, 1 barrier each (packed u64 counters)
  ull lo = 0, width = 1ull << 46;
  for (int it = 0; it < NITER2; ++it) {
    ull d = width >> 2;
    ull t1 = lo + d, t2 = lo + 2 * d, t3 = lo + 3 * d;
    int c1 = 0, c2 = 0, c3 = 0;
    #pragma unroll
    for (int q = 0; q < NQ; ++q) {
      ull k = key[q];
      c1 += (k >= t1) ? 1 : 0;
      c2 += (k >= t2) ? 1 : 0;
      c3 += (k >= t3) ? 1 : 0;
    }
    ull pk = (ull)c1 | ((ull)c2 << 21) | ((ull)c3 << 42);
    #pragma unroll
    for (int off = 32; off > 0; off >>= 1) pk += __shfl_down(pk, off);
    if (lane == 0) atomicAdd(&s_cnt[it], pk);
    __syncthreads();
    ull t = s_cnt[it];
    int C1 = (int)(t & 0x1FFFFFull);
    int C2 = (int)((t >> 21) & 0x1FFFFFull);
    int C3 = (int)(t >> 42);
    if (C3 >= KPRE)      lo = t3;
    else if (C2 >= KPRE) lo = t2;
    else if (C1 >= KPRE) lo = t1;
    width = d;
  }
  // lo == exact 1000th largest key; exactly KPRE keys >= lo

  // compact selected keys to LDS
  #pragma unroll
  for (int q = 0; q < NQ; ++q) {
    bool sel = (key[q] >= lo);
    ull m = __ballot(sel);
    int base = 0;
    if (lane == 0) base = atomicAdd(&s_pos, __popcll(m));
    base = __shfl(base, 0);
    if (sel) skeys[base + __popcll(m & ((1ull << lane) - 1ull))] = key[q];
  }
  if (tid >= KPRE) skeys[tid] = 0ull;
  __syncthreads();

  // bitonic sort 1024 keys descending — regs + shfl for j<=32, LDS for j>=64
  ull K = skeys[tid];
  for (int k = 2; k <= KPAD; k <<= 1) {
    bool descDir = ((tid & k) == 0);
    for (int j = k >> 1; j > 0; j >>= 1) {
      ull P;
      if (j >= 64) {
        __syncthreads();
        skeys[tid] = K;
        __syncthreads();
        P = skeys[tid ^ j];
      } else {
        P = __shfl_xor(K, j);
      }
      bool iAmLow = (tid & j) == 0;
      bool takeMax = (iAmLow == descDir);
      bool pGreater = P > K;
      if (takeMax == pGreater) K = P;
    }
  }

  if (tid < KPRE) {
    int n = (NANCH - 1) - (int)(uint32_t)(K & 0x3FFFull);
    size_t src = (size_t)b * NANCH + n;
    size_t dst = (size_t)b * KPAD + tid;
    g_tscore[dst] = ls[n];
    g_tn[dst] = n;
    g_tcls[dst] = g_cls[src];
    g_tdist[dst] = g_dist_in[src];
  }
}

// ---------------- Kernel 2b: DFL box decode for selected anchors only ----------------
__global__ __launch_bounds__(256) void k_boxdec(
    const float* __restrict__ pboxes,   // [B][N][64]
    const int* __restrict__ g_tn,       // [B][KPAD]
    float4* __restrict__ g_tbox)        // [B][KPAD]
{
  int gid = blockIdx.x * blockDim.x + threadIdx.x;
  if (gid >= BATCH * KPRE) return;
  int b = gid / KPRE;
  int s = gid % KPRE;
  int n = g_tn[(size_t)b * KPAD + s];

  const float4* pb = (const float4*)(pboxes + ((size_t)b * NANCH + n) * 64);
  float dist[4];
  #pragma unroll
  for (int k = 0; k < 4; ++k) {
    float v[16];
    #pragma unroll
    for (int q = 0; q < 4; ++q) {
      float4 t = pb[k * 4 + q];
      v[q * 4 + 0] = t.x; v[q * 4 + 1] = t.y; v[q * 4 + 2] = t.z; v[q * 4 + 3] = t.w;
    }
    float m = v[0];
    #pragma unroll
    for (int r = 1; r < 16; ++r) m = fmaxf(m, v[r]);
    float e[16];
    float su = 0.f;
    #pragma unroll
    for (int r = 0; r < 16; ++r) { e[r] = expf(v[r] - m); su += e[r]; }
    float acc = 0.f;
    #pragma unroll
    for (int r = 0; r < 16; ++r) acc += (e[r] / su) * (float)r;
    dist[k] = acc;
  }

  int n0, W; float sf;
  if (n < 6400)      { n0 = n;        W = 80; sf = 8.f;  }
  else if (n < 8000) { n0 = n - 6400; W = 40; sf = 16.f; }
  else               { n0 = n - 8000; W = 20; sf = 32.f; }
  float ax = (float)(n0 % W) + 0.5f;
  float ay = (float)(n0 / W) + 0.5f;

  float4 bx;
  bx.x = (ax - dist[0]) * sf;
  bx.y = (ay - dist[1]) * sf;
  bx.z = (ax + dist[2]) * sf;
  bx.w = (ay + dist[3]) * sf;

  g_tbox[(size_t)b * KPAD + s] = bx;
}

// ---------------- Kernel 3: suppression bit-matrix, one wave per (c,w,half) ----------------
// 136 upper-triangle (c,w) pairs x 2 half-chunks = 272 wave-tasks per batch.
// Lower-triangle g_sup words are NEVER written (always 0 semantically); k_nms masks them.
#define NPAIRS 136

__global__ __launch_bounds__(256) void k_iou(
    const float4* __restrict__ g_tbox,
    ull* __restrict__ g_sup,              // [B][KPAD][16] row-major (w>=c words only)
    ull* __restrict__ g_diag)             // [B][16][64] diag blocks
{
  int b = blockIdx.x;
  int wave = threadIdx.x >> 6;
  int lane = threadIdx.x & 63;
  int t = blockIdx.y * 4 + wave;          // 68*4 = 272 tasks exactly
  int p = t >> 1;                         // pair 0..135
  int h = t & 1;                          // half-chunk 0/1
  // p -> (c, w): enumerate c=0..15, w=c..15
  int c = 0, base = 0;
  while (p >= base + (16 - c)) { base += 16 - c; ++c; }
  int w = c + (p - base);

  const float4* tb = g_tbox + (size_t)b * KPAD;

  // column box (lane j)
  int j = w * 64 + lane;
  bool jv = j < KPRE;
  float4 bj = jv ? tb[j] : make_float4(0.f, 0.f, 0.f, 0.f);
  float aj = (bj.z - bj.x) * (bj.w - bj.y);

  // row box (lane i) — broadcast source registers
  int i = c * 64 + lane;
  float4 bi = (i < KPRE) ? tb[i] : make_float4(0.f, 0.f, 0.f, 0.f);
  float ai = (bi.z - bi.x) * (bi.w - bi.y);

  int rows = min(64, KPRE - c * 64);      // uniform (64, or 40 for c=15)
  int lo_ii = h * 32;
  int hi_ii = min(lo_ii + 32, rows);
  ull myword = 0;
  #pragma unroll 4
  for (int ii = lo_ii; ii < hi_ii; ++ii) {
    int irow = c * 64 + ii;               // uniform
    float rx = readlane_f(bi.x, ii);
    float ry = readlane_f(bi.y, ii);
    float rz = readlane_f(bi.z, ii);
    float rw = readlane_f(bi.w, ii);
    float ra = readlane_f(ai, ii);
    bool pred = false;
    if (jv && j > irow) {
      float ltx = fmaxf(rx, bj.x);
      float lty = fmaxf(ry, bj.y);
      float rbx = fminf(rz, bj.z);
      float rby = fminf(rw, bj.w);
      float wx = fmaxf(rbx - ltx, 0.f);
      float wy = fmaxf(rby - lty, 0.f);
      float inter = wx * wy;
      float den = ((ra + aj) - inter) + 1e-7f;
      pred = (inter / den) > IOUTHR;
    }
    ull word = __ballot(pred);
    if (lane == ii) myword = word;
  }

  int myrow = c * 64 + lane;
  if ((lane >> 5) == h && myrow < KPRE) {
    g_sup[((size_t)b * KPAD + myrow) * 16 + w] = myword;
    if (w == c) g_diag[((size_t)b * 16 + c) * 64 + lane] = myword;
  }
}

// ---------------- Kernel 4: scalar-chain NMS + parallel selection + output ----------------
__global__ __launch_bounds__(64) void k_nms(
    const ull* __restrict__ g_sup,
    const ull* __restrict__ g_diag,
    const float* __restrict__ g_tscore,
    const float4* __restrict__ g_tbox,
    const int* __restrict__ g_tcls,
    const float* __restrict__ g_tdist,
    float* __restrict__ out)
{
  int b = blockIdx.x;
  int lane = threadIdx.x;
  __shared__ __align__(16) ull rowbuf[2][64 * 16];   // 16 KB double buffer
  __shared__ float s_score[KPAD];
  __shared__ ull s_keptw[16];
  __shared__ ull s_valid[16];
  __shared__ int s_vpre[17];
  __shared__ int s_ipre[17];
  __shared__ int s_sel[MAXDET];
  __shared__ int s_flag[MAXDET];

  for (int t = lane; t < KPAD; t += 64)
    s_score[t] = g_tscore[(size_t)b * KPAD + t];

  const char* supb = (const char*)(g_sup + (size_t)b * KPAD * 16);
  const ull* diagb = g_diag + (size_t)b * 16 * 64;

  // prefetch chunk 0 (8 KB) into rowbuf[0] via global_load_lds width-16
  #pragma unroll
  for (int k = 0; k < 8; ++k) {
    const void* gp = supb + (size_t)k * 1024 + (size_t)lane * 16;
    void* lp = (char*)&rowbuf[0][0] + k * 1024;
    __builtin_amdgcn_global_load_lds(
        (const __attribute__((address_space(1))) uint32_t*)gp,
        (__attribute__((address_space(3))) uint32_t*)lp, 16, 0, 0);
  }
  ull diag = diagb[0 * 64 + lane];   // diag words for chunk 0

  // rem4: lane (q=lane>>4, w=lane&15) accumulates word w over kept rows ii with (ii&3)==q
  ull rem4 = 0;
  int w = lane & 15;
  int q = lane >> 4;
  int cur = 0;

  for (int c = 0; c < 16; ++c) {
    asm volatile("s_waitcnt vmcnt(0)" ::: "memory");  // chunk c staged, diag ready

    ull diag_next = 0;
    if (c < 15) {
      #pragma unroll
      for (int k = 0; k < 8; ++k) {
        const void* gp = supb + (size_t)(c + 1) * 8192 + (size_t)k * 1024 + (size_t)lane * 16;
        void* lp = (char*)&rowbuf[cur ^ 1][0] + k * 1024;
        __builtin_amdgcn_global_load_lds(
            (const __attribute__((address_space(1))) uint32_t*)gp,
            (__attribute__((address_space(3))) uint32_t*)lp, 16, 0, 0);
      }
      diag_next = diagb[(c + 1) * 64 + lane];
    }

    // removed word for this chunk from cross-chunk accumulation
    ull remw = readlane64(rem4, c) | readlane64(rem4, c + 16) |
               readlane64(rem4, c + 32) | readlane64(rem4, c + 48);
    ull chunkmask = (c == 15) ? ((1ull << (KPRE - 15 * 64)) - 1ull) : ~0ull;
    ull alive = ~remw & chunkmask;

    // serial greedy chain — wave-uniform scalar ops + readlane, nothing else
    ull kept = 0;
    while (alive) {
      int ii = __builtin_ctzll(alive);
      kept |= 1ull << ii;
      ull wcur = readlane64(diag, ii);
      alive &= ~(wcur | (1ull << ii));
    }
    if (lane == 0) s_keptw[c] = kept;

    // deferred parallel accumulation: OR upper-triangle words (w >= c) of kept rows.
    // Words w < c of rows in chunk c are semantically 0 and are NOT written by k_iou.
    #pragma unroll
    for (int t = 0; t < 16; ++t) {
      int ii = q + t * 4;
      ull v = rowbuf[cur][ii * 16 + w];    // always load (pipelined); predicated use
      if (w >= c && ((kept >> ii) & 1ull)) rem4 |= v;
    }

    cur ^= 1;
    diag = diag_next;
  }
  __syncthreads();

  // valid mask: kept && score > CONF
  for (int k = 0; k < 16; ++k) {
    int c = k * 64 + lane;
    bool sv = (c < KPRE) && (s_score[c] > CONF);
    ull m = __ballot(sv) & s_keptw[k];
    if (lane == 0) s_valid[k] = m;
  }
  __syncthreads();

  // prefix counts (valid / invalid among c < KPRE)
  if (lane == 0) {
    int v = 0, iv = 0;
    for (int k = 0; k < 16; ++k) {
      s_vpre[k] = v; s_ipre[k] = iv;
      int nval = (k == 15) ? (KPRE - 15 * 64) : 64;
      int pv = __popcll(s_valid[k]);
      v += pv; iv += nval - pv;
    }
    s_vpre[16] = v; s_ipre[16] = iv;
  }
  __syncthreads();

  // parallel scatter: valid entries in array order, then invalid (tied -1.0)
  int totValid = s_vpre[16];
  for (int k = 0; k < 16; ++k) {
    int c = k * 64 + lane;
    if (c >= KPRE) continue;
    ull wv = s_valid[k];
    ull ltmask = (1ull << lane) - 1ull;
    bool v = (wv >> lane) & 1ull;
    int below = __popcll(wv & ltmask);
    if (v) {
      int rank = s_vpre[k] + below;
      if (rank < MAXDET) { s_sel[rank] = c; s_flag[rank] = 1; }
    } else {
      int rank = totValid + s_ipre[k] + (lane - below);
      if (rank < MAXDET) { s_sel[rank] = c; s_flag[rank] = 0; }
    }
  }
  __syncthreads();

  float* obox = out;                                 // [B][100][4]
  float* osc  = out + (size_t)BATCH * MAXDET * 4;    // [B][100]
  float* ocls = out + (size_t)BATCH * MAXDET * 5;    // [B][100]
  float* odst = out + (size_t)BATCH * MAXDET * 6;    // [B][100][1]
  float* oval = out + (size_t)BATCH * MAXDET * 7;    // [B][100]

  for (int s = lane; s < MAXDET; s += 64) {
    int i = s_sel[s];
    int fl = s_flag[s];
    size_t src = (size_t)b * KPAD + i;
    float4 bx = g_tbox[src];
    float scv = fl ? s_score[i] : -1.0f;
    float clv = (float)g_tcls[src];
    float ddv = g_tdist[src];
    size_t o = (size_t)b * MAXDET + s;
    obox[o * 4 + 0] = bx.x;
    obox[o * 4 + 1] = bx.y;
    obox[o * 4 + 2] = bx.z;
    obox[o * 4 + 3] = bx.w;
    osc[o] = scv;
    ocls[o] = clv;
    odst[o] = ddv;
    oval[o] = fl ? 1.0f : 0.0f;
  }
}

extern "C" void kernel_launch(void* const* d_in, const int* in_sizes, int n_in,
                              void* d_out, int out_size, void* d_ws, size_t ws_size,
                              hipStream_t stream) {
  const float* pboxes = (const float*)d_in[0];   // (32,8400,64)
  const float* pcls   = (const float*)d_in[1];   // (32,8400,80)
  const float* pdist  = (const float*)d_in[2];   // (32,8400,1)
  // d_in[3] = images, unused by the reference computation
  float* out = (float*)d_out;

  char* ws = (char*)d_ws;
  size_t nBN = (size_t)BATCH * NANCH;
  size_t off = 0;
  float*  g_scores = (float*)(ws + off);  off += nBN * 4;
  int*    g_cls    = (int*)(ws + off);    off += nBN * 4;
  float*  g_tscore = (float*)(ws + off);  off += (size_t)BATCH * KPAD * 4;
  float4* g_tbox   = (float4*)(ws + off); off += (size_t)BATCH * KPAD * 16;
  int*    g_tn     = (int*)(ws + off);    off += (size_t)BATCH * KPAD * 4;
  int*    g_tcls   = (int*)(ws + off);    off += (size_t)BATCH * KPAD * 4;
  float*  g_tdist  = (float*)(ws + off);  off += (size_t)BATCH * KPAD * 4;
  ull*    g_sup    = (ull*)(ws + off);    off += (size_t)BATCH * KPAD * 16 * 8;
  ull*    g_diag   = (ull*)(ws + off);    off += (size_t)BATCH * 16 * 64 * 8;

  int total4 = BATCH * NANCH * 4;
  k_score<<<(total4 + 255) / 256, 256, 0, stream>>>(pcls, g_scores, g_cls);
  k_topk<<<BATCH, 1024, 0, stream>>>(g_scores, g_cls, pdist,
                                     g_tscore, g_tn, g_tcls, g_tdist);
  k_boxdec<<<(BATCH * KPRE + 255) / 256, 256, 0, stream>>>(pboxes, g_tn, g_tbox);
  dim3 giou(BATCH, (NPAIRS * 2) / 4);   // 68 blocks/batch
  k_iou<<<giou, 256, 0, stream>>>(g_tbox, g_sup, g_diag);
  k_nms<<<BATCH, 64, 0, stream>>>(g_sup, g_diag, g_tscore, g_tbox, g_tcls, g_tdist, out);
}